// Round 1
// baseline (48883.701 us; speedup 1.0000x reference)
//
#include <hip/hip_runtime.h>

#define B_   1024
#define S_   168
#define F_   64
#define I_   128
#define H_   512
#define G4   2048
#define PRED 24

typedef unsigned short u16;
typedef unsigned int   u32;
typedef __attribute__((ext_vector_type(8))) __bf16 bf16x8;
typedef __attribute__((ext_vector_type(4))) float  f32x4;

__device__ __forceinline__ u16 f2bf(float f) {
  u32 u = __float_as_uint(f);
  u += 0x7fff + ((u >> 16) & 1);     // round-to-nearest-even (values are tame: no NaN/Inf)
  return (u16)(u >> 16);
}
__device__ __forceinline__ float bf2f(u16 h) {
  return __uint_as_float(((u32)h) << 16);
}
__device__ __forceinline__ float sigm(float x) {
  x = fminf(fmaxf(x, -30.f), 30.f);
  return 1.f / (1.f + __expf(-x));
}
__device__ __forceinline__ float tanh_(float x) {
  x = fminf(fmaxf(x, -15.f), 15.f);
  float e = __expf(2.f * x);
  return (e - 1.f) / (e + 1.f);
}

// ---------------- prep kernels (run every call; cheap) ----------------

// split fp32 -> (hi, lo) bf16
__global__ void k_split(const float* __restrict__ src, u16* __restrict__ hi,
                        u16* __restrict__ lo, int n) {
  for (int i = blockIdx.x * 256 + threadIdx.x; i < n; i += gridDim.x * 256) {
    float a = src[i];
    u16 h = f2bf(a);
    hi[i] = h;
    lo[i] = f2bf(a - bf2f(h));
  }
}

// W0c[j][f] = sum_i Wih0[j][i] * Wenc[i][f]   (2048 x 64)
__global__ void k_w0c(const float* __restrict__ Wih0, const float* __restrict__ Wenc,
                      float* __restrict__ W0c, u16* __restrict__ hi, u16* __restrict__ lo) {
  int id = blockIdx.x * 256 + threadIdx.x;      // 2048*64 threads
  int j = id >> 6, f = id & 63;
  float s = 0.f;
  for (int i = 0; i < 128; ++i) s += Wih0[j * 128 + i] * Wenc[i * 64 + f];
  W0c[id] = s;
  u16 h = f2bf(s);
  hi[id] = h; lo[id] = f2bf(s - bf2f(h));
}

__global__ void k_biases(const float* __restrict__ Wih0, const float* __restrict__ benc,
                         const float* __restrict__ bih0, const float* __restrict__ bhh0,
                         const float* __restrict__ bih1, const float* __restrict__ bhh1,
                         float* __restrict__ b0c, float* __restrict__ b1c) {
  int j = blockIdx.x * 256 + threadIdx.x;       // 2048 threads
  float s = 0.f;
  for (int i = 0; i < 128; ++i) s += Wih0[j * 128 + i] * benc[i];
  b0c[j] = s + bih0[j] + bhh0[j];
  b1c[j] = bih1[j] + bhh1[j];
}

// W0cd[j][m] = sum_f W0c[j][f] * Wdec[f][m]   (2048 x 512)
__global__ void k_w0cd(const float* __restrict__ W0c, const float* __restrict__ Wdec,
                       u16* __restrict__ hi, u16* __restrict__ lo) {
  int id = blockIdx.x * 256 + threadIdx.x;      // 2048*512 threads
  int j = id >> 9, m = id & 511;
  float s = 0.f;
  for (int f = 0; f < 64; ++f) s += W0c[j * 64 + f] * Wdec[f * 512 + m];
  u16 h = f2bf(s);
  hi[id] = h; lo[id] = f2bf(s - bf2f(h));
}

__global__ void k_b0ar(const float* __restrict__ W0c, const float* __restrict__ bdec,
                       const float* __restrict__ b0c, float* __restrict__ b0ar) {
  int j = blockIdx.x * 256 + threadIdx.x;       // 2048 threads
  float s = 0.f;
  for (int f = 0; f < 64; ++f) s += W0c[j * 64 + f] * bdec[f];
  b0ar[j] = b0c[j] + s;
}

// ---------------- fused GEMM + LSTM-cell step kernel ----------------
// gates[b][g*512+j] = A1@W1^T + A2@W2^T + bias, then cell update.
// A, W in hi/lo bf16 split; 3-term MFMA (hi*hi + lo*hi + hi*lo) ~ fp32 accuracy.
// grid (16, 8): 64-row batch tile x 64-col j tile (x4 gates). 256 thr = 4 waves,
// wave w owns j-subtile w*16..w*16+15; acc frags [4 gates][4 m-tiles].
__global__ __launch_bounds__(256, 1) void lstm_layer(
    const u16* __restrict__ A1hi, const u16* __restrict__ A1lo, int strideA1, int K1,
    const u16* __restrict__ W1hi, const u16* __restrict__ W1lo,   // [2048 x K1]
    const u16* __restrict__ A2hi, const u16* __restrict__ A2lo,   // [1024 x 512]
    const u16* __restrict__ W2hi, const u16* __restrict__ W2lo,   // [2048 x 512]
    const float* __restrict__ bias,                                // [2048]
    float* __restrict__ c,                                         // [1024 x 512] in/out
    u16* __restrict__ hhi, u16* __restrict__ hlo)                  // [1024 x 512] out
{
  __shared__ u16 sA[2][64 * 32];     // [hi/lo][row][k]
  __shared__ u16 sW[2][256 * 32];    // rows = gate*64 + j-offset

  const int t     = threadIdx.x;
  const int mbase = blockIdx.x * 64;
  const int jbase = blockIdx.y * 64;
  const int arow  = t >> 2;          // 0..63 (staging row / j-offset)
  const int ac8   = (t & 3) * 8;     // 8-elem column chunk
  const int nk1   = K1 >> 5;
  const int nkt   = nk1 + 16;        // + K2=512 / 32

  const int lane = t & 63;
  const int wv   = t >> 6;
  const int quad = lane >> 4;
  const int lr   = lane & 15;

  f32x4 acc[4][4];
#pragma unroll
  for (int g = 0; g < 4; ++g)
#pragma unroll
    for (int mi = 0; mi < 4; ++mi)
      acc[g][mi] = (f32x4){0.f, 0.f, 0.f, 0.f};

  auto fetch = [&](int kt, int4& fa_h, int4& fa_l, int4* fw_h, int4* fw_l) {
    const u16 *Ah, *Al, *Wh, *Wl;
    int rs, K, kb;
    if (kt < nk1) { Ah = A1hi; Al = A1lo; Wh = W1hi; Wl = W1lo; rs = strideA1; K = K1;  kb = kt * 32; }
    else          { Ah = A2hi; Al = A2lo; Wh = W2hi; Wl = W2lo; rs = 512;      K = 512; kb = (kt - nk1) * 32; }
    int aoff = (mbase + arow) * rs + kb + ac8;
    fa_h = *(const int4*)(Ah + aoff);
    fa_l = *(const int4*)(Al + aoff);
#pragma unroll
    for (int q = 0; q < 4; ++q) {
      int woff = (q * 512 + jbase + arow) * K + kb + ac8;
      fw_h[q] = *(const int4*)(Wh + woff);
      fw_l[q] = *(const int4*)(Wl + woff);
    }
  };

  int4 va_h, va_l, vw_h[4], vw_l[4];
  fetch(0, va_h, va_l, vw_h, vw_l);

  for (int kt = 0; kt < nkt; ++kt) {
    *(int4*)&sA[0][arow * 32 + ac8] = va_h;
    *(int4*)&sA[1][arow * 32 + ac8] = va_l;
#pragma unroll
    for (int q = 0; q < 4; ++q) {
      *(int4*)&sW[0][(q * 64 + arow) * 32 + ac8] = vw_h[q];
      *(int4*)&sW[1][(q * 64 + arow) * 32 + ac8] = vw_l[q];
    }
    __syncthreads();

    int4 na_h, na_l, nw_h[4], nw_l[4];
    if (kt + 1 < nkt) fetch(kt + 1, na_h, na_l, nw_h, nw_l);

    bf16x8 ah[4], al[4];
#pragma unroll
    for (int mi = 0; mi < 4; ++mi) {
      ah[mi] = *(const bf16x8*)&sA[0][(mi * 16 + lr) * 32 + quad * 8];
      al[mi] = *(const bf16x8*)&sA[1][(mi * 16 + lr) * 32 + quad * 8];
    }
#pragma unroll
    for (int g = 0; g < 4; ++g) {
      bf16x8 bh = *(const bf16x8*)&sW[0][(g * 64 + wv * 16 + lr) * 32 + quad * 8];
      bf16x8 bl = *(const bf16x8*)&sW[1][(g * 64 + wv * 16 + lr) * 32 + quad * 8];
#pragma unroll
      for (int mi = 0; mi < 4; ++mi) {
        acc[g][mi] = __builtin_amdgcn_mfma_f32_16x16x32_bf16(ah[mi], bh, acc[g][mi], 0, 0, 0);
        acc[g][mi] = __builtin_amdgcn_mfma_f32_16x16x32_bf16(al[mi], bh, acc[g][mi], 0, 0, 0);
        acc[g][mi] = __builtin_amdgcn_mfma_f32_16x16x32_bf16(ah[mi], bl, acc[g][mi], 0, 0, 0);
      }
    }
    __syncthreads();
    if (kt + 1 < nkt) {
      va_h = na_h; va_l = na_l;
#pragma unroll
      for (int q = 0; q < 4; ++q) { vw_h[q] = nw_h[q]; vw_l[q] = nw_l[q]; }
    }
  }

  // epilogue: C/D layout col = lane&15, row = quad*4 + reg  [m89/m91-verified]
  const int   j   = jbase + wv * 16 + lr;
  const float bi  = bias[j];
  const float bff = bias[512 + j];
  const float bg  = bias[1024 + j];
  const float bo  = bias[1536 + j];
#pragma unroll
  for (int mi = 0; mi < 4; ++mi) {
#pragma unroll
    for (int r = 0; r < 4; ++r) {
      int b   = mbase + mi * 16 + quad * 4 + r;
      int idx = b * 512 + j;
      float iv = sigm(acc[0][mi][r] + bi);
      float fv = sigm(acc[1][mi][r] + bff);
      float gv = tanh_(acc[2][mi][r] + bg);
      float ov = sigm(acc[3][mi][r] + bo);
      float cn = fv * c[idx] + iv * gv;
      c[idx] = cn;
      float hn = ov * tanh_(cn);
      u16 hh = f2bf(hn);
      hhi[idx] = hh;
      hlo[idx] = f2bf(hn - bf2f(hh));
    }
  }
}

// ---------------- decoder: out[b][f] += (hhi+hlo)[b][:] . Wdec[f][:] ----------------
// grid (16, 8): 64-batch tile x 64-m chunk; fp32 atomic partial sums into d_out.
__global__ __launch_bounds__(256) void k_decoder(
    const u16* __restrict__ hhi, const u16* __restrict__ hlo,
    const float* __restrict__ Wdec, const float* __restrict__ bdec,
    float* __restrict__ out)   // d_out + k*64; batch row stride PRED*F_
{
  __shared__ float sH[64][65];
  const int t = threadIdx.x;
  const int bbase = blockIdx.x * 64;
  const int mbase = blockIdx.y * 64;
  {
    int b = bbase + (t >> 2);
#pragma unroll
    for (int v = 0; v < 2; ++v) {
      int m0 = (t & 3) * 16 + v * 8;
      int4 hv = *(const int4*)&hhi[b * 512 + mbase + m0];
      int4 lv = *(const int4*)&hlo[b * 512 + mbase + m0];
      const u16* hp = (const u16*)&hv;
      const u16* lp = (const u16*)&lv;
#pragma unroll
      for (int e = 0; e < 8; ++e)
        sH[t >> 2][m0 + e] = bf2f(hp[e]) + bf2f(lp[e]);
    }
  }
  __syncthreads();
  const int bl = t & 63;
  const int wv = t >> 6;       // wave-uniform -> scalar Wdec loads
  float acc[16];
#pragma unroll
  for (int u = 0; u < 16; ++u) acc[u] = 0.f;
  for (int m = 0; m < 64; ++m) {
    float hv = sH[bl][m];
#pragma unroll
    for (int u = 0; u < 16; ++u)
      acc[u] += hv * Wdec[(u * 4 + wv) * 512 + mbase + m];
  }
#pragma unroll
  for (int u = 0; u < 16; ++u) {
    int f = u * 4 + wv;
    float v = acc[u];
    if (blockIdx.y == 0) v += bdec[f];
    atomicAdd(&out[(bbase + bl) * (PRED * F_) + f], v);
  }
}

// ---------------- host orchestration ----------------

extern "C" void kernel_launch(void* const* d_in, const int* in_sizes, int n_in,
                              void* d_out, int out_size, void* d_ws, size_t ws_size,
                              hipStream_t stream) {
  const float* x    = (const float*)d_in[0];
  const float* Wenc = (const float*)d_in[1];
  const float* benc = (const float*)d_in[2];
  const float* Wih0 = (const float*)d_in[3];
  const float* Whh0 = (const float*)d_in[4];
  const float* bih0 = (const float*)d_in[5];
  const float* bhh0 = (const float*)d_in[6];
  const float* Wih1 = (const float*)d_in[7];
  const float* Whh1 = (const float*)d_in[8];
  const float* bih1 = (const float*)d_in[9];
  const float* bhh1 = (const float*)d_in[10];
  const float* Wdec = (const float*)d_in[11];
  const float* bdec = (const float*)d_in[12];
  float* out = (float*)d_out;

  // ---- workspace carve (~74 MB total) ----
  char* p = (char*)d_ws;
  auto carve = [&](size_t bytes) { char* r = p; p += (bytes + 255) & ~(size_t)255; return r; };
  const size_t NX = (size_t)B_ * S_ * F_;       // 11,010,048
  const size_t NH = (size_t)B_ * H_;            // 524,288
  u16* Xhi    = (u16*)carve(NX * 2);
  u16* Xlo    = (u16*)carve(NX * 2);
  float* W0c  = (float*)carve((size_t)G4 * 64 * 4);
  u16* W0chi  = (u16*)carve((size_t)G4 * 64 * 2);
  u16* W0clo  = (u16*)carve((size_t)G4 * 64 * 2);
  u16* W0cdhi = (u16*)carve((size_t)G4 * 512 * 2);
  u16* W0cdlo = (u16*)carve((size_t)G4 * 512 * 2);
  u16* Whh0hi = (u16*)carve((size_t)G4 * 512 * 2);
  u16* Whh0lo = (u16*)carve((size_t)G4 * 512 * 2);
  u16* Wih1hi = (u16*)carve((size_t)G4 * 512 * 2);
  u16* Wih1lo = (u16*)carve((size_t)G4 * 512 * 2);
  u16* Whh1hi = (u16*)carve((size_t)G4 * 512 * 2);
  u16* Whh1lo = (u16*)carve((size_t)G4 * 512 * 2);
  float* b0c  = (float*)carve(G4 * 4);
  float* b0ar = (float*)carve(G4 * 4);
  float* b1c  = (float*)carve(G4 * 4);
  u16* h0hi[2] = {(u16*)carve(NH * 2), (u16*)carve(NH * 2)};
  u16* h0lo[2] = {(u16*)carve(NH * 2), (u16*)carve(NH * 2)};
  u16* h1hi[2] = {(u16*)carve(NH * 2), (u16*)carve(NH * 2)};
  u16* h1lo[2] = {(u16*)carve(NH * 2), (u16*)carve(NH * 2)};
  float* c0 = (float*)carve(NH * 4);
  float* c1 = (float*)carve(NH * 4);
  (void)ws_size; (void)n_in; (void)in_sizes;

  // ---- init (d_out / d_ws are poisoned 0xAA before every launch) ----
  hipMemsetAsync(d_out, 0, (size_t)out_size * 4, stream);
  hipMemsetAsync(h0hi[0], 0, NH * 2, stream);
  hipMemsetAsync(h0lo[0], 0, NH * 2, stream);
  hipMemsetAsync(h1hi[0], 0, NH * 2, stream);
  hipMemsetAsync(h1lo[0], 0, NH * 2, stream);
  hipMemsetAsync(c0, 0, NH * 4, stream);
  hipMemsetAsync(c1, 0, NH * 4, stream);

  // ---- prep ----
  k_split<<<4096, 256, 0, stream>>>(x, Xhi, Xlo, (int)NX);
  k_split<<<2048, 256, 0, stream>>>(Whh0, Whh0hi, Whh0lo, G4 * 512);
  k_split<<<2048, 256, 0, stream>>>(Wih1, Wih1hi, Wih1lo, G4 * 512);
  k_split<<<2048, 256, 0, stream>>>(Whh1, Whh1hi, Whh1lo, G4 * 512);
  k_w0c<<<512, 256, 0, stream>>>(Wih0, Wenc, W0c, W0chi, W0clo);
  k_biases<<<8, 256, 0, stream>>>(Wih0, benc, bih0, bhh0, bih1, bhh1, b0c, b1c);
  k_w0cd<<<4096, 256, 0, stream>>>(W0c, Wdec, W0cdhi, W0cdlo);
  k_b0ar<<<8, 256, 0, stream>>>(W0c, bdec, b0c, b0ar);

  // ---- 168 teacher-forced + 23 autoregressive steps ----
  for (int s = 0; s < S_ + PRED - 1; ++s) {
    int pp = s & 1, np = 1 - pp;
    if (s < S_) {
      lstm_layer<<<dim3(16, 8), 256, 0, stream>>>(
          Xhi + (size_t)s * F_, Xlo + (size_t)s * F_, S_ * F_, 64, W0chi, W0clo,
          h0hi[pp], h0lo[pp], Whh0hi, Whh0lo,
          b0c, c0, h0hi[np], h0lo[np]);
    } else {
      lstm_layer<<<dim3(16, 8), 256, 0, stream>>>(
          h1hi[pp], h1lo[pp], 512, 512, W0cdhi, W0cdlo,
          h0hi[pp], h0lo[pp], Whh0hi, Whh0lo,
          b0ar, c0, h0hi[np], h0lo[np]);
    }
    lstm_layer<<<dim3(16, 8), 256, 0, stream>>>(
        h0hi[np], h0lo[np], 512, 512, Wih1hi, Wih1lo,
        h1hi[pp], h1lo[pp], Whh1hi, Whh1lo,
        b1c, c1, h1hi[np], h1lo[np]);
    if (s >= S_ - 1) {
      k_decoder<<<dim3(16, 8), 256, 0, stream>>>(
          h1hi[np], h1lo[np], Wdec, bdec, out + (size_t)(s - (S_ - 1)) * F_);
    }
  }
}

// Round 2
// 11929.381 us; speedup vs baseline: 4.0978x; 4.0978x over previous
//
#include <hip/hip_runtime.h>

#define B_   1024
#define S_   168
#define F_   64
#define I_   128
#define H_   512
#define G4   2048
#define PRED 24

typedef unsigned short u16;
typedef unsigned int   u32;
typedef __attribute__((ext_vector_type(8))) __bf16 bf16x8;
typedef __attribute__((ext_vector_type(4))) float  f32x4;
typedef __attribute__((ext_vector_type(4))) int    i32x4;

__device__ __forceinline__ u16 f2bf(float f) {
  u32 u = __float_as_uint(f);
  u += 0x7fff + ((u >> 16) & 1);
  return (u16)(u >> 16);
}
__device__ __forceinline__ float bf2f(u16 h) {
  return __uint_as_float(((u32)h) << 16);
}
__device__ __forceinline__ float sigm(float x) {
  x = fminf(fmaxf(x, -30.f), 30.f);
  return 1.f / (1.f + __expf(-x));
}
__device__ __forceinline__ float tanh_(float x) {
  x = fminf(fmaxf(x, -15.f), 15.f);
  float e = __expf(2.f * x);
  return (e - 1.f) / (e + 1.f);
}

// ---------------- prep kernels ----------------

__global__ void k_split(const float* __restrict__ src, u16* __restrict__ hi,
                        u16* __restrict__ lo, int n) {
  for (int i = blockIdx.x * 256 + threadIdx.x; i < n; i += gridDim.x * 256) {
    float a = src[i];
    u16 h = f2bf(a);
    hi[i] = h;
    lo[i] = f2bf(a - bf2f(h));
  }
}

// W0c[j][f] = sum_i Wih0[j][i] * Wenc[i][f]   (2048 x 64) fp32
__global__ void k_w0c(const float* __restrict__ Wih0, const float* __restrict__ Wenc,
                      float* __restrict__ W0c) {
  int id = blockIdx.x * 256 + threadIdx.x;
  int j = id >> 6, f = id & 63;
  float s = 0.f;
  for (int i = 0; i < 128; ++i) s += Wih0[j * 128 + i] * Wenc[i * 64 + f];
  W0c[id] = s;
}

// W0cd[j][m] = sum_f W0c[j][f] * Wdec[f][m]   (2048 x 512) fp32
__global__ void k_w0cd(const float* __restrict__ W0c, const float* __restrict__ Wdec,
                       float* __restrict__ W0cd) {
  int id = blockIdx.x * 256 + threadIdx.x;
  int j = id >> 9, m = id & 511;
  float s = 0.f;
  for (int f = 0; f < 64; ++f) s += W0c[j * 64 + f] * Wdec[f * 512 + m];
  W0cd[id] = s;
}

__global__ void k_biases(const float* __restrict__ Wih0, const float* __restrict__ benc,
                         const float* __restrict__ bih0, const float* __restrict__ bhh0,
                         const float* __restrict__ bih1, const float* __restrict__ bhh1,
                         float* __restrict__ b0c, float* __restrict__ b1c) {
  int j = blockIdx.x * 256 + threadIdx.x;
  float s = 0.f;
  for (int i = 0; i < 128; ++i) s += Wih0[j * 128 + i] * benc[i];
  b0c[j] = s + bih0[j] + bhh0[j];
  b1c[j] = bih1[j] + bhh1[j];
}

__global__ void k_b0ar(const float* __restrict__ W0c, const float* __restrict__ bdec,
                       const float* __restrict__ b0c, float* __restrict__ b0ar) {
  int j = blockIdx.x * 256 + threadIdx.x;
  float s = 0.f;
  for (int f = 0; f < 64; ++f) s += W0c[j * 64 + f] * bdec[f];
  b0ar[j] = b0c[j] + s;
}

// Pack W [2048 x K] row-major (row = g*512 + j) into MFMA B-fragment stream:
// frag block fi = (jt16*4 + g)*NK + kt -> 2KB: [0,1KB)=hi, [1KB,2KB)=lo.
// Within: lane*16B, lane covers B[n=lane&15][k=(lane>>4)*8 + e].
__global__ void k_pack(const float* __restrict__ W, int K, u16* __restrict__ dst) {
  int id = blockIdx.x * 256 + threadIdx.x;     // nfrag*64 threads
  int lane = id & 63, fi = id >> 6;
  int NK = K >> 5;
  int kt = fi % NK, jg = fi / NK;
  int g = jg & 3, jt = jg >> 2;
  int j = jt * 16 + (lane & 15);
  int kb = kt * 32 + (lane >> 4) * 8;
  const float* src = W + (size_t)(g * 512 + j) * K + kb;
  u16 hi[8] __attribute__((aligned(16)));
  u16 lo[8] __attribute__((aligned(16)));
#pragma unroll
  for (int e = 0; e < 8; ++e) {
    float v = src[e];
    u16 h = f2bf(v);
    hi[e] = h;
    lo[e] = f2bf(v - bf2f(h));
  }
  u16* d = dst + (size_t)fi * 1024 + lane * 8;
  *(i32x4*)d = *(const i32x4*)hi;
  *(i32x4*)(d + 512) = *(const i32x4*)lo;
}

// ---------------- fused GEMM + LSTM-cell, v2 ----------------
// grid (16 j-blocks, 16 m-blocks): WG tile = [64 batch x 32 j x 4 gates].
// 512 thr = 8 waves: wave = (mrow = wv>>1) x (jh = wv&1); wave tile [16 m x 16 j x 4 g].
// W: direct from global, pre-packed frags (L2-resident per XCD since j is fastest grid dim).
// A: LDS-staged per K-128 chunk, XOR-swizzled, double-buffered, 1 barrier/chunk.
__global__ __launch_bounds__(512, 2) void lstm2(
    const u16* __restrict__ A1hi, const u16* __restrict__ A1lo, int strideA1, int K1,
    const u16* __restrict__ W1p,
    const u16* __restrict__ A2hi, const u16* __restrict__ A2lo,
    const u16* __restrict__ W2p,
    const float* __restrict__ bias,
    float* __restrict__ c,
    u16* __restrict__ hhi, u16* __restrict__ hlo)
{
  __shared__ u16 sA[2][128 * 128];   // [buf][(part*64+row)*ppr*8 + ...] 32KB each

  const int t    = threadIdx.x;
  const int jblk = blockIdx.x, mblk = blockIdx.y;
  const int mbase = mblk * 64;
  const int lane = t & 63, wv = t >> 6;
  const int mrow = wv >> 1, jh = wv & 1;
  const int lr = lane & 15, qk = lane >> 4;
  const int row_l = mrow * 16 + lr;
  const int jtg  = jblk * 2 + jh;          // global 16-j tile id [0,32)
  const int nc1  = (K1 == 64) ? 1 : 4;
  const int NC   = nc1 + 4;
  const int NK1  = K1 >> 5;

  f32x4 acc[4];
#pragma unroll
  for (int g = 0; g < 4; ++g) acc[g] = (f32x4){0.f, 0.f, 0.f, 0.f};

  auto prm = [&](int cc, const u16*& Ah, const u16*& Al, int& st, int& kb, int& Kc,
                 const u16*& Wp, int& NK) {
    if (cc < nc1) { Ah = A1hi; Al = A1lo; st = strideA1; kb = cc * 128;
                    Kc = (K1 == 64) ? 64 : 128; Wp = W1p; NK = NK1; }
    else { int i = cc - nc1; Ah = A2hi; Al = A2lo; st = 512; kb = i * 128;
           Kc = 128; Wp = W2p; NK = 16; }
  };

  auto stageLoad = [&](int cc, i32x4* r) {
    const u16 *Ah, *Al, *Wp_; int st, kb, Kc, NK;
    prm(cc, Ah, Al, st, kb, Kc, Wp_, NK);
    const int ppr = Kc >> 3;               // pieces (16B) per row: 16 or 8
    const int npc = (Kc == 128) ? 4 : 2;
#pragma unroll 4
    for (int p = 0; p < npc; ++p) {
      int li   = p * 512 + t;
      int part = li >= 64 * ppr;
      int liw  = li - part * 64 * ppr;
      int rown = (ppr == 16) ? (liw >> 4) : (liw >> 3);
      int kp   = liw & (ppr - 1);
      const u16* src = (part ? Al : Ah) + (size_t)(mbase + rown) * st + kb + kp * 8;
      r[p] = __builtin_nontemporal_load((const i32x4*)src);
    }
  };
  auto stageWrite = [&](int cc, const i32x4* r, int buf) {
    const int Kc  = (cc < nc1 && K1 == 64) ? 64 : 128;
    const int ppr = Kc >> 3;
    const int npc = (Kc == 128) ? 4 : 2;
#pragma unroll 4
    for (int p = 0; p < npc; ++p) {
      int li   = p * 512 + t;
      int part = li >= 64 * ppr;
      int liw  = li - part * 64 * ppr;
      int rown = (ppr == 16) ? (liw >> 4) : (liw >> 3);
      int kp   = liw & (ppr - 1);
      *(i32x4*)&sA[buf][(((part * 64 + rown) * ppr) + (kp ^ (rown & (ppr - 1)))) * 8] = r[p];
    }
  };
  auto loadW = [&](const u16* Wp_, int NK, int kt, i32x4* wh, i32x4* wl) {
#pragma unroll
    for (int g = 0; g < 4; ++g) {
      const u16* p = Wp_ + (size_t)((jtg * 4 + g) * NK + kt) * 1024 + lane * 8;
      wh[g] = *(const i32x4*)p;
      wl[g] = *(const i32x4*)(p + 512);
    }
  };
  auto mstep = [&](int buf, int ppr, int s, const i32x4* wh, const i32x4* wl) {
    int pl = (s * 4 + qk) ^ (row_l & (ppr - 1));
    bf16x8 ah = *(const bf16x8*)&sA[buf][(row_l * ppr + pl) * 8];
    bf16x8 al = *(const bf16x8*)&sA[buf][((64 + row_l) * ppr + pl) * 8];
#pragma unroll
    for (int g = 0; g < 4; ++g) {
      bf16x8 bh = __builtin_bit_cast(bf16x8, wh[g]);
      bf16x8 bl = __builtin_bit_cast(bf16x8, wl[g]);
      acc[g] = __builtin_amdgcn_mfma_f32_16x16x32_bf16(ah, bh, acc[g], 0, 0, 0);
      acc[g] = __builtin_amdgcn_mfma_f32_16x16x32_bf16(al, bh, acc[g], 0, 0, 0);
      acc[g] = __builtin_amdgcn_mfma_f32_16x16x32_bf16(ah, bl, acc[g], 0, 0, 0);
    }
  };

  i32x4 sreg[4];
  stageLoad(0, sreg);
  stageWrite(0, sreg, 0);
  __syncthreads();

  i32x4 whA[4], wlA[4], whB[4], wlB[4];
  {
    const u16 *Ah, *Al, *Wp_; int st, kb, Kc, NK;
    prm(0, Ah, Al, st, kb, Kc, Wp_, NK);
    loadW(Wp_, NK, kb >> 5, whA, wlA);
  }

  for (int cc = 0; cc < NC; ++cc) {
    const u16 *Ah, *Al, *Wp_; int st, kb, Kc, NK;
    prm(cc, Ah, Al, st, kb, Kc, Wp_, NK);
    const int ns  = Kc >> 5;
    const int buf = cc & 1;
    const int ppr = Kc >> 3;
    if (cc + 1 < NC) stageLoad(cc + 1, sreg);
    for (int s = 0; s < ns; s += 2) {
      loadW(Wp_, NK, (kb >> 5) + s + 1, whB, wlB);      // prefetch s+1
      mstep(buf, ppr, s, whA, wlA);
      if (s + 2 < ns) {
        loadW(Wp_, NK, (kb >> 5) + s + 2, whA, wlA);    // prefetch s+2
      } else if (cc + 1 < NC) {                          // cross-chunk prefetch
        const u16 *Ah2, *Al2, *Wp2; int st2, kb2, Kc2, NK2;
        prm(cc + 1, Ah2, Al2, st2, kb2, Kc2, Wp2, NK2);
        loadW(Wp2, NK2, kb2 >> 5, whA, wlA);
      }
      mstep(buf, ppr, s + 1, whB, wlB);
    }
    if (cc + 1 < NC) {
      stageWrite(cc + 1, sreg, buf ^ 1);
      __syncthreads();
    }
  }

  // epilogue: C/D col = lane&15 -> j, row = qk*4 + r -> batch  [m89/m91-verified]
  const int   j   = jblk * 32 + jh * 16 + lr;
  const float bi  = bias[j];
  const float bff = bias[512 + j];
  const float bg  = bias[1024 + j];
  const float bo  = bias[1536 + j];
#pragma unroll
  for (int r = 0; r < 4; ++r) {
    int b   = mbase + mrow * 16 + qk * 4 + r;
    int idx = b * 512 + j;
    float iv = sigm(acc[0][r] + bi);
    float fv = sigm(acc[1][r] + bff);
    float gv = tanh_(acc[2][r] + bg);
    float ov = sigm(acc[3][r] + bo);
    float cn = fv * c[idx] + iv * gv;
    c[idx] = cn;
    float hn = ov * tanh_(cn);
    u16 hh = f2bf(hn);
    hhi[idx] = hh;
    hlo[idx] = f2bf(hn - bf2f(hh));
  }
}

// ---------------- decoder (unchanged from R1) ----------------
__global__ __launch_bounds__(256) void k_decoder(
    const u16* __restrict__ hhi, const u16* __restrict__ hlo,
    const float* __restrict__ Wdec, const float* __restrict__ bdec,
    float* __restrict__ out)
{
  __shared__ float sH[64][65];
  const int t = threadIdx.x;
  const int bbase = blockIdx.x * 64;
  const int mbase = blockIdx.y * 64;
  {
    int b = bbase + (t >> 2);
#pragma unroll
    for (int v = 0; v < 2; ++v) {
      int m0 = (t & 3) * 16 + v * 8;
      i32x4 hv = *(const i32x4*)&hhi[b * 512 + mbase + m0];
      i32x4 lv = *(const i32x4*)&hlo[b * 512 + mbase + m0];
      const u16* hp = (const u16*)&hv;
      const u16* lp = (const u16*)&lv;
#pragma unroll
      for (int e = 0; e < 8; ++e)
        sH[t >> 2][m0 + e] = bf2f(hp[e]) + bf2f(lp[e]);
    }
  }
  __syncthreads();
  const int bl = t & 63;
  const int wv = t >> 6;
  float acc[16];
#pragma unroll
  for (int u = 0; u < 16; ++u) acc[u] = 0.f;
  for (int m = 0; m < 64; ++m) {
    float hv = sH[bl][m];
#pragma unroll
    for (int u = 0; u < 16; ++u)
      acc[u] += hv * Wdec[(u * 4 + wv) * 512 + mbase + m];
  }
#pragma unroll
  for (int u = 0; u < 16; ++u) {
    int f = u * 4 + wv;
    float v = acc[u];
    if (blockIdx.y == 0) v += bdec[f];
    atomicAdd(&out[(bbase + bl) * (PRED * F_) + f], v);
  }
}

// ---------------- host orchestration ----------------

extern "C" void kernel_launch(void* const* d_in, const int* in_sizes, int n_in,
                              void* d_out, int out_size, void* d_ws, size_t ws_size,
                              hipStream_t stream) {
  const float* x    = (const float*)d_in[0];
  const float* Wenc = (const float*)d_in[1];
  const float* benc = (const float*)d_in[2];
  const float* Wih0 = (const float*)d_in[3];
  const float* Whh0 = (const float*)d_in[4];
  const float* bih0 = (const float*)d_in[5];
  const float* bhh0 = (const float*)d_in[6];
  const float* Wih1 = (const float*)d_in[7];
  const float* Whh1 = (const float*)d_in[8];
  const float* bih1 = (const float*)d_in[9];
  const float* bhh1 = (const float*)d_in[10];
  const float* Wdec = (const float*)d_in[11];
  const float* bdec = (const float*)d_in[12];
  float* out = (float*)d_out;

  char* p = (char*)d_ws;
  auto carve = [&](size_t bytes) { char* r = p; p += (bytes + 255) & ~(size_t)255; return r; };
  const size_t NX = (size_t)B_ * S_ * F_;
  const size_t NH = (size_t)B_ * H_;
  const size_t WP512 = (size_t)G4 * 512 * 2;   // packed u16 count (hi+lo)
  u16* Xhi    = (u16*)carve(NX * 2);
  u16* Xlo    = (u16*)carve(NX * 2);
  float* W0c  = (float*)carve((size_t)G4 * 64 * 4);
  float* W0cd = (float*)carve((size_t)G4 * 512 * 4);
  u16* W0cp   = (u16*)carve((size_t)G4 * 64 * 2 * 2);
  u16* W0cdp  = (u16*)carve(WP512 * 2);
  u16* Whh0p  = (u16*)carve(WP512 * 2);
  u16* Wih1p  = (u16*)carve(WP512 * 2);
  u16* Whh1p  = (u16*)carve(WP512 * 2);
  float* b0c  = (float*)carve(G4 * 4);
  float* b0ar = (float*)carve(G4 * 4);
  float* b1c  = (float*)carve(G4 * 4);
  u16* h0hi[2] = {(u16*)carve(NH * 2), (u16*)carve(NH * 2)};
  u16* h0lo[2] = {(u16*)carve(NH * 2), (u16*)carve(NH * 2)};
  u16* h1hi[2] = {(u16*)carve(NH * 2), (u16*)carve(NH * 2)};
  u16* h1lo[2] = {(u16*)carve(NH * 2), (u16*)carve(NH * 2)};
  float* c0 = (float*)carve(NH * 4);
  float* c1 = (float*)carve(NH * 4);
  (void)ws_size; (void)n_in; (void)in_sizes;

  hipMemsetAsync(d_out, 0, (size_t)out_size * 4, stream);
  hipMemsetAsync(h0hi[0], 0, NH * 2, stream);
  hipMemsetAsync(h0lo[0], 0, NH * 2, stream);
  hipMemsetAsync(h1hi[0], 0, NH * 2, stream);
  hipMemsetAsync(h1lo[0], 0, NH * 2, stream);
  hipMemsetAsync(c0, 0, NH * 4, stream);
  hipMemsetAsync(c1, 0, NH * 4, stream);

  // prep
  k_split<<<4096, 256, 0, stream>>>(x, Xhi, Xlo, (int)NX);
  k_w0c<<<512, 256, 0, stream>>>(Wih0, Wenc, W0c);
  k_w0cd<<<4096, 256, 0, stream>>>(W0c, Wdec, W0cd);
  k_biases<<<8, 256, 0, stream>>>(Wih0, benc, bih0, bhh0, bih1, bhh1, b0c, b1c);
  k_b0ar<<<8, 256, 0, stream>>>(W0c, bdec, b0c, b0ar);
  k_pack<<<32 * 16, 256, 0, stream>>>(Whh0, 512, Whh0p);
  k_pack<<<32 * 16, 256, 0, stream>>>(Wih1, 512, Wih1p);
  k_pack<<<32 * 16, 256, 0, stream>>>(Whh1, 512, Whh1p);
  k_pack<<<32 * 16, 256, 0, stream>>>(W0cd, 512, W0cdp);
  k_pack<<<32 * 2, 256, 0, stream>>>(W0c, 64, W0cp);

  // grid: x = j (fastest; XCD = jblk%8 keeps W slices L2-resident), y = m
  dim3 grid(16, 16);
  for (int s = 0; s < S_ + PRED - 1; ++s) {
    int pp = s & 1, np = 1 - pp;
    if (s < S_) {
      lstm2<<<grid, 512, 0, stream>>>(
          Xhi + (size_t)s * F_, Xlo + (size_t)s * F_, S_ * F_, 64, W0cp,
          h0hi[pp], h0lo[pp], Whh0p,
          b0c, c0, h0hi[np], h0lo[np]);
    } else {
      lstm2<<<grid, 512, 0, stream>>>(
          h1hi[pp], h1lo[pp], 512, 512, W0cdp,
          h0hi[pp], h0lo[pp], Whh0p,
          b0ar, c0, h0hi[np], h0lo[np]);
    }
    lstm2<<<grid, 512, 0, stream>>>(
        h0hi[np], h0lo[np], 512, 512, Wih1p,
        h1hi[pp], h1lo[pp], Whh1p,
        b1c, c1, h1hi[np], h1lo[np]);
    if (s >= S_ - 1) {
      k_decoder<<<dim3(16, 8), 256, 0, stream>>>(
          h1hi[np], h1lo[np], Wdec, bdec, out + (size_t)(s - (S_ - 1)) * F_);
    }
  }
}

// Round 3
// 8833.205 us; speedup vs baseline: 5.5341x; 1.3505x over previous
//
#include <hip/hip_runtime.h>

#define B_   1024
#define S_   168
#define F_   64
#define I_   128
#define H_   512
#define G4   2048
#define PRED 24

typedef unsigned short u16;
typedef unsigned int   u32;
typedef __attribute__((ext_vector_type(8))) __bf16 bf16x8;
typedef __attribute__((ext_vector_type(4))) float  f32x4;
typedef __attribute__((ext_vector_type(4))) int    i32x4;

__device__ __forceinline__ u16 f2bf(float f) {
  u32 u = __float_as_uint(f);
  u += 0x7fff + ((u >> 16) & 1);
  return (u16)(u >> 16);
}
__device__ __forceinline__ float bf2f(u16 h) {
  return __uint_as_float(((u32)h) << 16);
}
__device__ __forceinline__ float sigm(float x) {
  x = fminf(fmaxf(x, -30.f), 30.f);
  return 1.f / (1.f + __expf(-x));
}
__device__ __forceinline__ float tanh_(float x) {
  x = fminf(fmaxf(x, -15.f), 15.f);
  float e = __expf(2.f * x);
  return (e - 1.f) / (e + 1.f);
}

// ---------------- prep kernels ----------------

__global__ void k_split(const float* __restrict__ src, u16* __restrict__ hi,
                        u16* __restrict__ lo, int n) {
  for (int i = blockIdx.x * 256 + threadIdx.x; i < n; i += gridDim.x * 256) {
    float a = src[i];
    u16 h = f2bf(a);
    hi[i] = h;
    lo[i] = f2bf(a - bf2f(h));
  }
}

__global__ void k_w0c(const float* __restrict__ Wih0, const float* __restrict__ Wenc,
                      float* __restrict__ W0c) {
  int id = blockIdx.x * 256 + threadIdx.x;
  int j = id >> 6, f = id & 63;
  float s = 0.f;
  for (int i = 0; i < 128; ++i) s += Wih0[j * 128 + i] * Wenc[i * 64 + f];
  W0c[id] = s;
}

__global__ void k_w0cd(const float* __restrict__ W0c, const float* __restrict__ Wdec,
                       float* __restrict__ W0cd) {
  int id = blockIdx.x * 256 + threadIdx.x;
  int j = id >> 9, m = id & 511;
  float s = 0.f;
  for (int f = 0; f < 64; ++f) s += W0c[j * 64 + f] * Wdec[f * 512 + m];
  W0cd[id] = s;
}

__global__ void k_biases(const float* __restrict__ Wih0, const float* __restrict__ benc,
                         const float* __restrict__ bih0, const float* __restrict__ bhh0,
                         const float* __restrict__ bih1, const float* __restrict__ bhh1,
                         float* __restrict__ b0c, float* __restrict__ b1c) {
  int j = blockIdx.x * 256 + threadIdx.x;
  float s = 0.f;
  for (int i = 0; i < 128; ++i) s += Wih0[j * 128 + i] * benc[i];
  b0c[j] = s + bih0[j] + bhh0[j];
  b1c[j] = bih1[j] + bhh1[j];
}

__global__ void k_b0ar(const float* __restrict__ W0c, const float* __restrict__ bdec,
                       const float* __restrict__ b0c, float* __restrict__ b0ar) {
  int j = blockIdx.x * 256 + threadIdx.x;
  float s = 0.f;
  for (int f = 0; f < 64; ++f) s += W0c[j * 64 + f] * bdec[f];
  b0ar[j] = b0c[j] + s;
}

// Pack W [2048 x K] row-major (row = g*512 + j) into MFMA B-fragment stream:
// frag fi = (jt16*4 + g)*NK + kt -> 2KB: [0,1KB)=hi, [1KB,2KB)=lo.
__global__ void k_pack(const float* __restrict__ W, int K, u16* __restrict__ dst) {
  int id = blockIdx.x * 256 + threadIdx.x;
  int lane = id & 63, fi = id >> 6;
  int NK = K >> 5;
  int kt = fi % NK, jg = fi / NK;
  int g = jg & 3, jt = jg >> 2;
  int j = jt * 16 + (lane & 15);
  int kb = kt * 32 + (lane >> 4) * 8;
  const float* src = W + (size_t)(g * 512 + j) * K + kb;
  u16 hi[8] __attribute__((aligned(16)));
  u16 lo[8] __attribute__((aligned(16)));
#pragma unroll
  for (int e = 0; e < 8; ++e) {
    float v = src[e];
    u16 h = f2bf(v);
    hi[e] = h;
    lo[e] = f2bf(v - bf2f(h));
  }
  u16* d = dst + (size_t)fi * 1024 + lane * 8;
  *(i32x4*)d = *(const i32x4*)hi;
  *(i32x4*)(d + 512) = *(const i32x4*)lo;
}

// ---------------- fused GEMM + LSTM-cell, v3 ----------------
// grid (16 j, 16 m). WG tile [64m x 32j x 4g]; 8 waves = 4 kk (K-split) x 2 jh.
// Wave tile [64m x 16j x 4g] over a K-quarter: W frags reused across 4 m-tiles
// in registers -> W L2 traffic 4x lower than R2. Partial accs reduced via LDS.
__global__ __launch_bounds__(512, 2) void lstm3(
    const u16* __restrict__ A1hi, const u16* __restrict__ A1lo, int strideA1, int K1,
    const u16* __restrict__ W1p,
    const u16* __restrict__ A2hi, const u16* __restrict__ A2lo,
    const u16* __restrict__ W2p,
    const float* __restrict__ bias,
    float* __restrict__ c,
    u16* __restrict__ hhi, u16* __restrict__ hlo)
{
  __shared__ __align__(16) u16 smem_[49152];  // 96KB: 2x32KB A-stage, reused as 96KB reduce

  const int t = threadIdx.x;
  const int jblk = blockIdx.x, mblk = blockIdx.y;
  const int mbase = mblk * 64;
  const int lane = t & 63, wv = t >> 6;
  const int kk = wv >> 1, jh = wv & 1;       // K-split id, j-half id
  const int lr = lane & 15, qk = lane >> 4;
  const int jtg = jblk * 2 + jh;
  const int nc1 = (K1 == 64) ? 1 : 4;
  const int NC  = nc1 + 4;
  const int NK1 = K1 >> 5;

  f32x4 acc[4][4];   // [mi][gate]
#pragma unroll
  for (int mi = 0; mi < 4; ++mi)
#pragma unroll
    for (int g = 0; g < 4; ++g) acc[mi][g] = (f32x4){0.f, 0.f, 0.f, 0.f};

  auto prm = [&](int cc, const u16*& Ah, const u16*& Al, int& st, int& kb, int& Kc,
                 const u16*& Wp, int& NK) {
    if (cc < nc1) { Ah = A1hi; Al = A1lo; st = strideA1; kb = cc * 128;
                    Kc = (K1 == 64) ? 64 : 128; Wp = W1p; NK = NK1; }
    else { int i = cc - nc1; Ah = A2hi; Al = A2lo; st = 512; kb = i * 128;
           Kc = 128; Wp = W2p; NK = 16; }
  };
  auto nsof = [&](int cc) { return (cc < nc1 && K1 == 64) ? 2 : 4; };

  auto stageLoad = [&](int cc, i32x4* rr) {
    const u16 *Ah, *Al, *Wp_; int st, kb, Kc, NK;
    prm(cc, Ah, Al, st, kb, Kc, Wp_, NK);
    const int ppr = Kc >> 3;
    const int npc = (Kc == 128) ? 4 : 2;
#pragma unroll 4
    for (int p = 0; p < npc; ++p) {
      int li   = p * 512 + t;
      int part = li >= 64 * ppr;
      int liw  = li - part * 64 * ppr;
      int rown = (ppr == 16) ? (liw >> 4) : (liw >> 3);
      int kp   = liw & (ppr - 1);
      const u16* src = (part ? Al : Ah) + (size_t)(mbase + rown) * st + kb + kp * 8;
      rr[p] = *(const i32x4*)src;
    }
  };
  auto stageWrite = [&](int cc, const i32x4* rr, int buf) {
    const int Kc  = (cc < nc1 && K1 == 64) ? 64 : 128;
    const int ppr = Kc >> 3;
    const int npc = (Kc == 128) ? 4 : 2;
    u16* sb = smem_ + buf * 16384;
#pragma unroll 4
    for (int p = 0; p < npc; ++p) {
      int li   = p * 512 + t;
      int part = li >= 64 * ppr;
      int liw  = li - part * 64 * ppr;
      int rown = (ppr == 16) ? (liw >> 4) : (liw >> 3);
      int kp   = liw & (ppr - 1);
      *(i32x4*)&sb[(((part * 64 + rown) * ppr) + (kp ^ (rown & (ppr - 1)))) * 8] = rr[p];
    }
  };
  auto loadW = [&](const u16* Wp_, int NK, int kt, i32x4* wh, i32x4* wl) {
#pragma unroll
    for (int g = 0; g < 4; ++g) {
      const u16* p = Wp_ + (size_t)((jtg * 4 + g) * NK + kt) * 1024 + lane * 8;
      wh[g] = *(const i32x4*)p;
      wl[g] = *(const i32x4*)(p + 512);
    }
  };
  auto mstep = [&](int buf, int ppr, const i32x4* wh, const i32x4* wl) {
    const u16* sb = smem_ + buf * 16384;
    bf16x8 ah[4], al[4];
#pragma unroll
    for (int mi = 0; mi < 4; ++mi) {
      int rowA = mi * 16 + lr;
      int pl   = (kk * 4 + qk) ^ (rowA & (ppr - 1));
      ah[mi] = *(const bf16x8*)&sb[(rowA * ppr + pl) * 8];
      al[mi] = *(const bf16x8*)&sb[((64 + rowA) * ppr + pl) * 8];
    }
#pragma unroll
    for (int g = 0; g < 4; ++g) {
      bf16x8 bh = __builtin_bit_cast(bf16x8, wh[g]);
      bf16x8 bl = __builtin_bit_cast(bf16x8, wl[g]);
#pragma unroll
      for (int mi = 0; mi < 4; ++mi) {
        acc[mi][g] = __builtin_amdgcn_mfma_f32_16x16x32_bf16(ah[mi], bh, acc[mi][g], 0, 0, 0);
        acc[mi][g] = __builtin_amdgcn_mfma_f32_16x16x32_bf16(al[mi], bh, acc[mi][g], 0, 0, 0);
        acc[mi][g] = __builtin_amdgcn_mfma_f32_16x16x32_bf16(ah[mi], bl, acc[mi][g], 0, 0, 0);
      }
    }
  };

  i32x4 sreg[4];
  i32x4 whA[4], wlA[4], whB[4], wlB[4];

  stageLoad(0, sreg);
  stageWrite(0, sreg, 0);
  {
    const u16 *Ah, *Al, *Wp_; int st, kb, Kc, NK;
    prm(0, Ah, Al, st, kb, Kc, Wp_, NK);
    if (kk < nsof(0)) loadW(Wp_, NK, (kb >> 5) + kk, whA, wlA);
  }
  __syncthreads();

  for (int cc = 0; cc < NC; ++cc) {
    const int buf  = cc & 1;
    const bool more = (cc + 1 < NC);
    if (more) {
      stageLoad(cc + 1, sreg);
      const u16 *Ah, *Al, *Wp_; int st, kb, Kc, NK;
      prm(cc + 1, Ah, Al, st, kb, Kc, Wp_, NK);
      if (kk < nsof(cc + 1)) loadW(Wp_, NK, (kb >> 5) + kk, whB, wlB);
    }
    {
      const u16 *Ah, *Al, *Wp_; int st, kb, Kc, NK;
      prm(cc, Ah, Al, st, kb, Kc, Wp_, NK);
      if (kk < nsof(cc)) mstep(buf, Kc >> 3, whA, wlA);
    }
    if (more) stageWrite(cc + 1, sreg, buf ^ 1);
    __syncthreads();
    if (more) {
#pragma unroll
      for (int g = 0; g < 4; ++g) { whA[g] = whB[g]; wlA[g] = wlB[g]; }
    }
  }

  // ---- 4-way K-split reduction through LDS ----
  // region layout: [(jh*4 + mi)*3 + slot] blocks of 4KB (4g x 64 lanes x f32x4)
  float* red = (float*)smem_;
#pragma unroll
  for (int mi = 0; mi < 4; ++mi) {
    if (mi != kk) {
      int slot = kk - (kk > mi ? 1 : 0);
      float* base = red + (size_t)(((jh * 4 + mi) * 3 + slot) * 1024) + lane * 4;
#pragma unroll
      for (int g = 0; g < 4; ++g) *(f32x4*)(base + g * 256) = acc[mi][g];
    }
  }
  __syncthreads();

  f32x4 r[4];
#pragma unroll
  for (int g = 0; g < 4; ++g) r[g] = acc[0][g];
  if (kk == 1) {
#pragma unroll
    for (int g = 0; g < 4; ++g) r[g] = acc[1][g];
  } else if (kk == 2) {
#pragma unroll
    for (int g = 0; g < 4; ++g) r[g] = acc[2][g];
  } else if (kk == 3) {
#pragma unroll
    for (int g = 0; g < 4; ++g) r[g] = acc[3][g];
  }
#pragma unroll
  for (int s = 0; s < 3; ++s) {
    float* base = red + (size_t)(((jh * 4 + kk) * 3 + s) * 1024) + lane * 4;
#pragma unroll
    for (int g = 0; g < 4; ++g) r[g] += *(const f32x4*)(base + g * 256);
  }

  // ---- epilogue: owner wave (kk,jh) covers m-tile mi=kk, j-half jh ----
  const int   j   = jblk * 32 + jh * 16 + lr;
  const float bi  = bias[j];
  const float bff = bias[512 + j];
  const float bg  = bias[1024 + j];
  const float bo  = bias[1536 + j];
#pragma unroll
  for (int rr = 0; rr < 4; ++rr) {
    int b   = mbase + kk * 16 + qk * 4 + rr;
    int idx = b * 512 + j;
    float iv = sigm(r[0][rr] + bi);
    float fv = sigm(r[1][rr] + bff);
    float gv = tanh_(r[2][rr] + bg);
    float ov = sigm(r[3][rr] + bo);
    float cn = fv * c[idx] + iv * gv;
    c[idx] = cn;
    float hn = ov * tanh_(cn);
    u16 hh = f2bf(hn);
    hhi[idx] = hh;
    hlo[idx] = f2bf(hn - bf2f(hh));
  }
}

// ---------------- decoder ----------------
__global__ __launch_bounds__(256) void k_decoder(
    const u16* __restrict__ hhi, const u16* __restrict__ hlo,
    const float* __restrict__ Wdec, const float* __restrict__ bdec,
    float* __restrict__ out)
{
  __shared__ float sH[64][65];
  const int t = threadIdx.x;
  const int bbase = blockIdx.x * 64;
  const int mbase = blockIdx.y * 64;
  {
    int b = bbase + (t >> 2);
#pragma unroll
    for (int v = 0; v < 2; ++v) {
      int m0 = (t & 3) * 16 + v * 8;
      i32x4 hv = *(const i32x4*)&hhi[b * 512 + mbase + m0];
      i32x4 lv = *(const i32x4*)&hlo[b * 512 + mbase + m0];
      const u16* hp = (const u16*)&hv;
      const u16* lp = (const u16*)&lv;
#pragma unroll
      for (int e = 0; e < 8; ++e)
        sH[t >> 2][m0 + e] = bf2f(hp[e]) + bf2f(lp[e]);
    }
  }
  __syncthreads();
  const int bl = t & 63;
  const int wv = t >> 6;
  float acc[16];
#pragma unroll
  for (int u = 0; u < 16; ++u) acc[u] = 0.f;
  for (int m = 0; m < 64; ++m) {
    float hv = sH[bl][m];
#pragma unroll
    for (int u = 0; u < 16; ++u)
      acc[u] += hv * Wdec[(u * 4 + wv) * 512 + mbase + m];
  }
#pragma unroll
  for (int u = 0; u < 16; ++u) {
    int f = u * 4 + wv;
    float v = acc[u];
    if (blockIdx.y == 0) v += bdec[f];
    atomicAdd(&out[(bbase + bl) * (PRED * F_) + f], v);
  }
}

// ---------------- host orchestration ----------------

extern "C" void kernel_launch(void* const* d_in, const int* in_sizes, int n_in,
                              void* d_out, int out_size, void* d_ws, size_t ws_size,
                              hipStream_t stream) {
  const float* x    = (const float*)d_in[0];
  const float* Wenc = (const float*)d_in[1];
  const float* benc = (const float*)d_in[2];
  const float* Wih0 = (const float*)d_in[3];
  const float* Whh0 = (const float*)d_in[4];
  const float* bih0 = (const float*)d_in[5];
  const float* bhh0 = (const float*)d_in[6];
  const float* Wih1 = (const float*)d_in[7];
  const float* Whh1 = (const float*)d_in[8];
  const float* bih1 = (const float*)d_in[9];
  const float* bhh1 = (const float*)d_in[10];
  const float* Wdec = (const float*)d_in[11];
  const float* bdec = (const float*)d_in[12];
  float* out = (float*)d_out;

  char* p = (char*)d_ws;
  auto carve = [&](size_t bytes) { char* r = p; p += (bytes + 255) & ~(size_t)255; return r; };
  const size_t NX = (size_t)B_ * S_ * F_;
  const size_t NH = (size_t)B_ * H_;
  const size_t WP512 = (size_t)G4 * 512 * 2;
  u16* Xhi    = (u16*)carve(NX * 2);
  u16* Xlo    = (u16*)carve(NX * 2);
  float* W0c  = (float*)carve((size_t)G4 * 64 * 4);
  float* W0cd = (float*)carve((size_t)G4 * 512 * 4);
  u16* W0cp   = (u16*)carve((size_t)G4 * 64 * 2 * 2);
  u16* W0cdp  = (u16*)carve(WP512 * 2);
  u16* Whh0p  = (u16*)carve(WP512 * 2);
  u16* Wih1p  = (u16*)carve(WP512 * 2);
  u16* Whh1p  = (u16*)carve(WP512 * 2);
  float* b0c  = (float*)carve(G4 * 4);
  float* b0ar = (float*)carve(G4 * 4);
  float* b1c  = (float*)carve(G4 * 4);
  u16* h0hi[2] = {(u16*)carve(NH * 2), (u16*)carve(NH * 2)};
  u16* h0lo[2] = {(u16*)carve(NH * 2), (u16*)carve(NH * 2)};
  u16* h1hi[2] = {(u16*)carve(NH * 2), (u16*)carve(NH * 2)};
  u16* h1lo[2] = {(u16*)carve(NH * 2), (u16*)carve(NH * 2)};
  float* c0 = (float*)carve(NH * 4);
  float* c1 = (float*)carve(NH * 4);
  (void)ws_size; (void)n_in; (void)in_sizes;

  hipMemsetAsync(d_out, 0, (size_t)out_size * 4, stream);
  hipMemsetAsync(h0hi[0], 0, NH * 2, stream);
  hipMemsetAsync(h0lo[0], 0, NH * 2, stream);
  hipMemsetAsync(h1hi[0], 0, NH * 2, stream);
  hipMemsetAsync(h1lo[0], 0, NH * 2, stream);
  hipMemsetAsync(c0, 0, NH * 4, stream);
  hipMemsetAsync(c1, 0, NH * 4, stream);

  k_split<<<4096, 256, 0, stream>>>(x, Xhi, Xlo, (int)NX);
  k_w0c<<<512, 256, 0, stream>>>(Wih0, Wenc, W0c);
  k_w0cd<<<4096, 256, 0, stream>>>(W0c, Wdec, W0cd);
  k_biases<<<8, 256, 0, stream>>>(Wih0, benc, bih0, bhh0, bih1, bhh1, b0c, b1c);
  k_b0ar<<<8, 256, 0, stream>>>(W0c, bdec, b0c, b0ar);
  k_pack<<<32 * 16, 256, 0, stream>>>(Whh0, 512, Whh0p);
  k_pack<<<32 * 16, 256, 0, stream>>>(Wih1, 512, Wih1p);
  k_pack<<<32 * 16, 256, 0, stream>>>(Whh1, 512, Whh1p);
  k_pack<<<32 * 16, 256, 0, stream>>>(W0cd, 512, W0cdp);
  k_pack<<<32 * 2, 256, 0, stream>>>(W0c, 64, W0cp);

  dim3 grid(16, 16);
  for (int s = 0; s < S_ + PRED - 1; ++s) {
    int pp = s & 1, np = 1 - pp;
    if (s < S_) {
      lstm3<<<grid, 512, 0, stream>>>(
          Xhi + (size_t)s * F_, Xlo + (size_t)s * F_, S_ * F_, 64, W0cp,
          h0hi[pp], h0lo[pp], Whh0p,
          b0c, c0, h0hi[np], h0lo[np]);
    } else {
      lstm3<<<grid, 512, 0, stream>>>(
          h1hi[pp], h1lo[pp], 512, 512, W0cdp,
          h0hi[pp], h0lo[pp], Whh0p,
          b0ar, c0, h0hi[np], h0lo[np]);
    }
    lstm3<<<grid, 512, 0, stream>>>(
        h0hi[np], h0lo[np], 512, 512, Wih1p,
        h1hi[pp], h1lo[pp], Whh1p,
        b1c, c1, h1hi[np], h1lo[np]);
    if (s >= S_ - 1) {
      k_decoder<<<dim3(16, 8), 256, 0, stream>>>(
          h1hi[np], h1lo[np], Wdec, bdec, out + (size_t)(s - (S_ - 1)) * F_);
    }
  }
}